// Round 3
// baseline (671.230 us; speedup 1.0000x reference)
//
#include <hip/hip_runtime.h>

#define NF 64
#define NH 32
#define NK 16
#define NNODES 15
#define BLOCK 512

// W2 node stride padded so (stride % 32) == 4: the 8 distinct level-3 nodes
// land on disjoint 4-bank groups -> divergent ds_read_b128 is conflict-free.
#define W2_STRIDE 1028   // 32*32 = 1024 -> +4
#define SUB_STRIDE 17    // 16 -> +1

__global__ __launch_bounds__(BLOCK, 4) void tree_mlp_kernel(
    const float* __restrict__ x,
    const float* __restrict__ W1, const float* __restrict__ b1,
    const float* __restrict__ W2, const float* __restrict__ b2,
    const float* __restrict__ W3, const float* __restrict__ b3,
    const float* __restrict__ leaf_best, const int* __restrict__ subset_idx,
    float* __restrict__ out, int N)
{
    // Static shared, <64 KiB — no dynamic-LDS opt-in (broke graph replay in R1).
    __shared__ __align__(16) float W2L[NNODES * W2_STRIDE];   // 61680 B
    __shared__ int   subL[NNODES * SUB_STRIDE + 1];           // 1024 B
    __shared__ float b3L[32];
    __shared__ float leafL[16];

    const int tid = threadIdx.x;

    for (int i = tid; i < NNODES * 1024; i += BLOCK)
        W2L[(i >> 10) * W2_STRIDE + (i & 1023)] = W2[i];
    for (int i = tid; i < NNODES * NK; i += BLOCK)
        subL[(i >> 4) * SUB_STRIDE + (i & 15)] = subset_idx[i];
    for (int i = tid; i < NNODES * 2; i += BLOCK) b3L[i] = b3[i];
    for (int i = tid; i < 16; i += BLOCK) leafL[i] = leaf_best[i];
    __syncthreads();

    const int s = blockIdx.x * BLOCK + tid;
    if (s >= N) return;

    const float* xr = x + (size_t)s * NF;

    int loc = 0, off = 0;
    #pragma unroll 1   // keep level loop rolled (I$); body is ~1.6k FMAs
    for (int level = 0; level < 4; ++level) {
        const int node = off + loc;

        // Gather 16 subset features (per-lane scatter, L1/L2-served).
        // Constant-indexed local array -> register-promoted (NO pointer punning:
        // R2's float4 punning blocked SROA and spilled everything to scratch).
        float xs[NK];
        const int* si = subL + node * SUB_STRIDE;
        #pragma unroll
        for (int k = 0; k < NK; ++k) xs[k] = xr[si[k]];

        // h1 = leaky(W1[node] @ xs + b1)   (32x16 GEMV, W1 from global, float4 temps)
        float h1v[NH];
        const float4* w1g = (const float4*)(W1 + node * (NH * NK));  // rows 64B-aligned
        const float* b1g = b1 + node * NH;
        #pragma unroll
        for (int j = 0; j < NH; ++j) {
            float acc = b1g[j];
            #pragma unroll
            for (int q = 0; q < NK / 4; ++q) {
                const float4 t = w1g[j * 4 + q];
                acc += t.x * xs[q * 4 + 0];
                acc += t.y * xs[q * 4 + 1];
                acc += t.z * xs[q * 4 + 2];
                acc += t.w * xs[q * 4 + 3];
            }
            h1v[j] = (acc >= 0.f) ? acc : 0.01f * acc;
        }

        // h2 = leaky(W2[node] @ h1 + b2)   (32x32 GEMV, W2 from LDS via ds_read_b128)
        float h2v[NH];
        const float4* w2n = (const float4*)(W2L + node * W2_STRIDE);  // 16B-aligned
        const float* b2g = b2 + node * NH;
        #pragma unroll
        for (int g = 0; g < NH; ++g) {
            float acc = b2g[g];
            #pragma unroll
            for (int q = 0; q < NH / 4; ++q) {
                const float4 t = w2n[g * 8 + q];
                acc += t.x * h1v[q * 4 + 0];
                acc += t.y * h1v[q * 4 + 1];
                acc += t.z * h1v[q * 4 + 2];
                acc += t.w * h1v[q * 4 + 3];
            }
            h2v[g] = (acc >= 0.f) ? acc : 0.01f * acc;
        }

        // logits; p0 < 0.5  <=>  l0 < l1  (softmax is monotone)
        const float4* w3g = (const float4*)(W3 + node * 2 * NH);
        float l0 = b3L[node * 2 + 0];
        float l1 = b3L[node * 2 + 1];
        #pragma unroll
        for (int q = 0; q < NH / 4; ++q) {
            const float4 t0 = w3g[q];
            l0 += t0.x * h2v[q * 4 + 0];
            l0 += t0.y * h2v[q * 4 + 1];
            l0 += t0.z * h2v[q * 4 + 2];
            l0 += t0.w * h2v[q * 4 + 3];
        }
        #pragma unroll
        for (int q = 0; q < NH / 4; ++q) {
            const float4 t1 = w3g[8 + q];
            l1 += t1.x * h2v[q * 4 + 0];
            l1 += t1.y * h2v[q * 4 + 1];
            l1 += t1.z * h2v[q * 4 + 2];
            l1 += t1.w * h2v[q * 4 + 3];
        }

        const int bit = (l0 < l1) ? 1 : 0;
        loc = 2 * loc + bit;
        off = 2 * off + 1;   // node offsets: 0, 1, 3, 7
    }

    out[s] = leafL[loc];
}

extern "C" void kernel_launch(void* const* d_in, const int* in_sizes, int n_in,
                              void* d_out, int out_size, void* d_ws, size_t ws_size,
                              hipStream_t stream) {
    const float* x         = (const float*)d_in[0];
    const float* W1        = (const float*)d_in[1];
    const float* b1        = (const float*)d_in[2];
    const float* W2        = (const float*)d_in[3];
    const float* b2        = (const float*)d_in[4];
    const float* W3        = (const float*)d_in[5];
    const float* b3        = (const float*)d_in[6];
    const float* leaf_best = (const float*)d_in[7];
    const int*   subset    = (const int*)d_in[8];

    const int N = in_sizes[0] / NF;
    const int grid = (N + BLOCK - 1) / BLOCK;
    tree_mlp_kernel<<<grid, BLOCK, 0, stream>>>(
        x, W1, b1, W2, b2, W3, b3, leaf_best, subset, (float*)d_out, N);
}

// Round 4
// 499.024 us; speedup vs baseline: 1.3451x; 1.3451x over previous
//
#include <hip/hip_runtime.h>

#define NF 64
#define NH 32
#define NK 16
#define NNODES 15
#define BLOCK 512
#define NWAVES (BLOCK / 64)

// LDS budget (bytes): W2 61440 + sub 960 + perm 2048 + sort 512 = 64960 <= 65536.
// No stride padding needed: after the in-block sort, waves are node-uniform
// (boundary waves have <=2 nodes -> 2-way LDS dedup is free per m136).

__global__ __attribute__((amdgpu_flat_work_group_size(512, 512),
                          amdgpu_waves_per_eu(2, 4)))
void tree_mlp_kernel(
    const float* __restrict__ x,
    const float* __restrict__ W1, const float* __restrict__ b1,
    const float* __restrict__ W2, const float* __restrict__ b2,
    const float* __restrict__ W3, const float* __restrict__ b3,
    const float* __restrict__ leaf_best, const int* __restrict__ subset_idx,
    float* __restrict__ out, int N)
{
    __shared__ __align__(16) float W2L[NNODES * 1024];   // 61440 B
    __shared__ int      subL[NNODES * NK];               // 960 B
    __shared__ unsigned permL[BLOCK];                    // 2048 B
    __shared__ int      sortL[NWAVES * 16];              // 512 B

    const int tid  = threadIdx.x;
    const int lane = tid & 63;
    const int wv   = tid >> 6;

    for (int i = tid; i < NNODES * 1024; i += BLOCK) W2L[i] = W2[i];
    for (int i = tid; i < NNODES * NK;   i += BLOCK) subL[i] = subset_idx[i];
    __syncthreads();

    const int s = blockIdx.x * BLOCK + tid;
    int valid = (s < N) ? 1 : 0;
    int id    = valid ? s : 0;      // invalid lanes shadow sample 0 (stay live for ballots)
    int loc = 0, off = 0;

    #pragma unroll 1   // keep level loop rolled (I$); body is ~1.6k FMAs
    for (int level = 0; level < 4; ++level) {
        if (level > 0) {
            // ---- in-block counting sort by loc (nb buckets), ballot-based ----
            const int nb = 1 << level;
            int myrank = 0;
            #pragma unroll 1
            for (int b = 0; b < nb; ++b) {
                const unsigned long long m = __ballot(loc == b);
                if (loc == b)
                    myrank = __popcll(m & ((1ull << lane) - 1ull));
                if (lane == 0)
                    sortL[b * NWAVES + wv] = __popcll(m);
            }
            __syncthreads();
            if (tid == 0) {            // exclusive prefix over (bucket, wave)
                int run = 0;
                for (int i = 0; i < nb * NWAVES; ++i) {
                    const int c = sortL[i];
                    sortL[i] = run;
                    run += c;
                }
            }
            __syncthreads();
            const int slot = sortL[loc * NWAVES + wv] + myrank;
            permL[slot] = ((unsigned)id << 5) | ((unsigned)valid << 4) | (unsigned)loc;
            __syncthreads();
            const unsigned p = permL[tid];
            id    = (int)(p >> 5);
            valid = (int)((p >> 4) & 1u);
            loc   = (int)(p & 15u);
            __syncthreads();           // protect permL/sortL reuse next level
        }

        const int node = off + loc;    // wave-uniform after sort (except boundary waves)
        const float* xr = x + (size_t)id * NF;

        // Gather the 16 subset features for this node
        float xs[NK];
        const int* si = subL + node * NK;
        #pragma unroll
        for (int k = 0; k < NK; ++k) xs[k] = xr[si[k]];

        // h1 = leaky(W1[node] @ xs + b1)   (32x16 GEMV, W1 uniform from global/L1)
        float h1v[NH];
        const float4* w1g = (const float4*)(W1 + node * (NH * NK));
        const float* b1g = b1 + node * NH;
        #pragma unroll
        for (int j = 0; j < NH; ++j) {
            float acc = b1g[j];
            #pragma unroll
            for (int q = 0; q < NK / 4; ++q) {
                const float4 t = w1g[j * 4 + q];
                acc += t.x * xs[q * 4 + 0];
                acc += t.y * xs[q * 4 + 1];
                acc += t.z * xs[q * 4 + 2];
                acc += t.w * xs[q * 4 + 3];
            }
            h1v[j] = (acc >= 0.f) ? acc : 0.01f * acc;
        }

        // h2 = leaky(W2[node] @ h1 + b2)   (32x32 GEMV, W2 from LDS, broadcast reads)
        float h2v[NH];
        const float4* w2n = (const float4*)(W2L + node * 1024);
        const float* b2g = b2 + node * NH;
        #pragma unroll
        for (int g = 0; g < NH; ++g) {
            float acc = b2g[g];
            #pragma unroll
            for (int q = 0; q < NH / 4; ++q) {
                const float4 t = w2n[g * 8 + q];
                acc += t.x * h1v[q * 4 + 0];
                acc += t.y * h1v[q * 4 + 1];
                acc += t.z * h1v[q * 4 + 2];
                acc += t.w * h1v[q * 4 + 3];
            }
            h2v[g] = (acc >= 0.f) ? acc : 0.01f * acc;
        }

        // logits; p0 < 0.5  <=>  l0 < l1  (softmax is monotone)
        const float4* w3g = (const float4*)(W3 + node * 2 * NH);
        float l0 = b3[node * 2 + 0];
        float l1 = b3[node * 2 + 1];
        #pragma unroll
        for (int q = 0; q < NH / 4; ++q) {
            const float4 t0 = w3g[q];
            l0 += t0.x * h2v[q * 4 + 0];
            l0 += t0.y * h2v[q * 4 + 1];
            l0 += t0.z * h2v[q * 4 + 2];
            l0 += t0.w * h2v[q * 4 + 3];
        }
        #pragma unroll
        for (int q = 0; q < NH / 4; ++q) {
            const float4 t1 = w3g[8 + q];
            l1 += t1.x * h2v[q * 4 + 0];
            l1 += t1.y * h2v[q * 4 + 1];
            l1 += t1.z * h2v[q * 4 + 2];
            l1 += t1.w * h2v[q * 4 + 3];
        }

        const int bit = (l0 < l1) ? 1 : 0;
        loc = 2 * loc + bit;
        off = 2 * off + 1;   // node offsets: 0, 1, 3, 7
    }

    if (valid) out[id] = leaf_best[loc];
}

extern "C" void kernel_launch(void* const* d_in, const int* in_sizes, int n_in,
                              void* d_out, int out_size, void* d_ws, size_t ws_size,
                              hipStream_t stream) {
    const float* x         = (const float*)d_in[0];
    const float* W1        = (const float*)d_in[1];
    const float* b1        = (const float*)d_in[2];
    const float* W2        = (const float*)d_in[3];
    const float* b2        = (const float*)d_in[4];
    const float* W3        = (const float*)d_in[5];
    const float* b3        = (const float*)d_in[6];
    const float* leaf_best = (const float*)d_in[7];
    const int*   subset    = (const int*)d_in[8];

    const int N = in_sizes[0] / NF;
    const int grid = (N + BLOCK - 1) / BLOCK;
    tree_mlp_kernel<<<grid, BLOCK, 0, stream>>>(
        x, W1, b1, W2, b2, W3, b3, leaf_best, subset, (float*)d_out, N);
}